// Round 3
// baseline (1897.541 us; speedup 1.0000x reference)
//
#include <hip/hip_runtime.h>
#include <hip/hip_fp16.h>

#define TENC 64
#define TDEC 18
#define NDEC 24
#define NF1  17
#define NF2  129
#define HH   128

// ---- ws layout ----
// fp32 region (float indices)
#define OFF_WX   0        // [32][128] float4  (Wx packed [kk][j])
#define OFF_WI   16384    // [16][64] float4
#define OFF_WI2  20480    // [16][64] float4
// u32 region (uint indices into ws viewed as uint*)
#define U_GB     24576    // [37][1024] f16-pair gate weights, phase B
#define U_GD     62464    // [65][1024] phase D
#define U_GF     129024   // [64][1024] phase F
#define U_WE     194560   // [64][128]  We  (pr = i*8+pq)
#define U_WE2    202752   // [64][128]  We2
#define U_WH     210944   // [128][128] Wh  (pr = i*4+pq)

#define SB   68     // WiX/Wi2X row stride (floats)
#define SWF  132    // WxF row stride
#define XIN  1200   // xin region offset inside big[bb]
#define BIGN 8772

typedef _Float16 h2t __attribute__((ext_vector_type(2)));

#if defined(__has_builtin)
#if __has_builtin(__builtin_amdgcn_fdot2)
#define HAVE_FDOT2 1
#endif
#endif

__device__ __forceinline__ float fdot2p(unsigned w, unsigned x, float acc)
{
    h2t hw = __builtin_bit_cast(h2t, w);
    h2t hx = __builtin_bit_cast(h2t, x);
#ifdef HAVE_FDOT2
    return __builtin_amdgcn_fdot2(hw, hx, acc, false);
#else
    return acc + (float)hw.x * (float)hx.x + (float)hw.y * (float)hx.y;
#endif
}

__device__ __forceinline__ unsigned pkh_d(float a, float b)
{
    __half ha = __float2half(a), hb = __float2half(b);
    return (unsigned)__half_as_ushort(ha) | ((unsigned)__half_as_ushort(hb) << 16);
}

__device__ __forceinline__ float fsig(float x) { return 1.f / (1.f + __expf(-x)); }
__device__ __forceinline__ float ftanh(float x)
{
    x = fminf(fmaxf(x, -15.f), 15.f);
    float e = __expf(2.f * x);
    return (e - 1.f) / (e + 1.f);
}
__device__ __forceinline__ float dot4(float4 a, float4 b)
{ return a.x * b.x + a.y * b.y + a.z * b.z + a.w * b.w; }

// ---------------- pack kernels ----------------
// fp32 float4 pack for Wx, Wi, Wi2: dst[kk*G + g] = {W[g][4kk..4kk+3]}
__global__ void pack_f3(const float* Wx, const float* Wi, const float* Wi2, float* ws)
{
    const int m = blockIdx.y;
    const float* src; int G, K, off;
    if (m == 0)      { src = Wx;  G = 128; K = 128; off = OFF_WX; }
    else if (m == 1) { src = Wi;  G = 64;  K = 64;  off = OFF_WI; }
    else             { src = Wi2; G = 64;  K = 64;  off = OFF_WI2; }
    const int n = G * K;
    for (int i = blockIdx.x * blockDim.x + threadIdx.x; i < n; i += gridDim.x * blockDim.x) {
        int q = i & 3, gk = i >> 2;
        int kk = gk / G, g = gk - kk * G;
        ws[off + i] = src[g * K + kk * 4 + q];
    }
}

// gate weights: column for tid = [Wih row (padded to KXP) | Whh row]; pair q = p*NP + i
__global__ void pack_gate(const float* Wih, const float* Whh, int Kx, int KXP, int TP, int NP,
                          unsigned base, unsigned* wsu)
{
    const int i = blockIdx.x;
    const int tid = threadIdx.x;
    const int p = tid >> 9, g = tid & 511;
    const int q = p * NP + i;
    unsigned v = 0;
    if (q < TP) {
        int k0 = 2 * q, k1 = 2 * q + 1;
        float f0 = (k0 < KXP) ? ((k0 < Kx) ? Wih[g * Kx + k0] : 0.f) : Whh[g * HH + (k0 - KXP)];
        float f1 = (k1 < KXP) ? ((k1 < Kx) ? Wih[g * Kx + k1] : 0.f) : Whh[g * HH + (k1 - KXP)];
        v = pkh_d(f0, f1);
    }
    wsu[base + (unsigned)i * 1024u + tid] = v;
}

// e-weights: dst[j*128 + pq*nI + i] = pair (i*nPQ + pq) of row j (K=256 -> 128 pairs)
__global__ void pack_ew(const float* W, int J, int nPQ, int nI, unsigned base, unsigned* wsu)
{
    int idx = blockIdx.x * blockDim.x + threadIdx.x;
    if (idx >= J * 128) return;
    int j = idx >> 7, r = idx & 127;
    int pq = r / nI, i = r - pq * nI;
    int pr = i * nPQ + pq;
    wsu[base + idx] = pkh_d(W[j * 256 + 2 * pr], W[j * 256 + 2 * pr + 1]);
}

// ---------------- main kernel ----------------
__global__ __launch_bounds__(1024)
void dstp_main(const float* __restrict__ inq, const float* __restrict__ labp,
               const float* __restrict__ bih1, const float* __restrict__ bhh1,
               const float* __restrict__ bih2, const float* __restrict__ bhh2,
               const float* __restrict__ bihd, const float* __restrict__ bhhd,
               const float* __restrict__ Wi_b, const float* __restrict__ Vd_w, const float* __restrict__ Vd_b,
               const float* __restrict__ Wi2_b, const float* __restrict__ Vd2_w, const float* __restrict__ Vd2_b,
               const float* __restrict__ Wx_b, const float* __restrict__ V_w, const float* __restrict__ V_b,
               const float* __restrict__ reg_w, const float* __restrict__ reg_b,
               const float* __restrict__ ws, float* __restrict__ out)
{
    __shared__ __align__(16) float buf[2][TENC][HH];   // mid then final (fp32)
    __shared__ __align__(16) float big[2][BIGN];       // WiX+xin / Wi2X / WxF
    __shared__ unsigned hcp[2][128];                   // f16 pairs: [h 0..63 | c 64..127]
    __shared__ unsigned xhp[2][130];                   // f16 pairs: [x-part | h-part]
    __shared__ __align__(16) float ebuf[2][128];
    __shared__ float sc[2][NF2];
    __shared__ float att[2][64];
    __shared__ float pre2[2][2][512];                  // [khalf][bb][gate]
    __shared__ float lab[2][TENC];
    __shared__ __align__(16) float vw1[64], vw2[64], vwf[128], rw[128];
    __shared__ float rsm[4];

    const int tid  = threadIdx.x;
    const int lane = tid & 63;
    const int b0   = blockIdx.x * 2;
    const int p    = tid >> 9;     // k-half (wave-uniform)
    const int g    = tid & 511;    // gate index
    const int r9   = tid & 511;
    const unsigned* wsu = (const unsigned*)ws;
    const float4* Wxp = (const float4*)(ws + OFF_WX);
    const float4* Wip = (const float4*)(ws + OFF_WI);
    const float4* Wi2p = (const float4*)(ws + OFF_WI2);

    const float bg1 = p ? 0.f : (bih1[g] + bhh1[g]);
    const float bg2 = p ? 0.f : (bih2[g] + bhh2[g]);
    const float bgd = p ? 0.f : (bihd[g] + bhhd[g]);
    float creg = 0.f;   // fp32 cell state, lives in pointwise thread (tid<256)

    // ================= Phase A: inputs, WiX =================
    if (tid < 128) lab[tid >> 6][tid & 63] = labp[(b0 + (tid >> 6)) * TENC + (tid & 63)];
    if (tid < 64)        vw1[tid]       = Vd_w[tid];
    else if (tid < 128)  vw2[tid - 64]  = Vd2_w[tid - 64];
    else if (tid < 256)  vwf[tid - 128] = V_w[tid - 128];
    else if (tid < 384)  rw[tid - 256]  = reg_w[tid - 256];
    for (int i = tid; i < 2176; i += 1024) {            // xin: x[t][f], COLS skip 14
        int bb = i / 1088, r = i - bb * 1088, t = r / NF1, f = r - t * NF1;
        big[bb][XIN + r] = inq[((b0 + bb) * TENC + t) * 18 + f + (f >= 14)];
    }
    __syncthreads();
    for (int i = tid; i < 2176; i += 1024) {            // WiX[f][j]
        int bb = i / 1088, r = i - bb * 1088, f = r >> 6, j = r & 63;
        float acc = Wi_b[j];
        for (int tt = 0; tt < 16; ++tt) {
            float4 w = Wip[tt * 64 + j];
            acc += big[bb][XIN + (4 * tt + 0) * NF1 + f] * w.x
                 + big[bb][XIN + (4 * tt + 1) * NF1 + f] * w.y
                 + big[bb][XIN + (4 * tt + 2) * NF1 + f] * w.z
                 + big[bb][XIN + (4 * tt + 3) * NF1 + f] * w.w;
        }
        big[bb][f * SB + j] = acc;
    }

    // ================= Phase B: encoder scan 1 =================
    {
        if (tid < 130) { xhp[0][tid] = 0u; xhp[1][tid] = 0u; }
        if (tid < 128) { hcp[0][tid] = 0u; hcp[1][tid] = 0u; }
        creg = 0.f;
        unsigned wB[37];
        #pragma unroll
        for (int i = 0; i < 37; ++i) wB[i] = wsu[U_GB + i * 1024 + tid];
        unsigned we[16];
        {
            const uint4* q4 = (const uint4*)(wsu + U_WE + ((r9 >> 3) << 7) + ((r9 & 7) << 4));
            uint4 A = q4[0], Bq = q4[1], C = q4[2], D4 = q4[3];
            we[0]=A.x; we[1]=A.y; we[2]=A.z; we[3]=A.w; we[4]=Bq.x; we[5]=Bq.y; we[6]=Bq.z; we[7]=Bq.w;
            we[8]=C.x; we[9]=C.y; we[10]=C.z; we[11]=C.w; we[12]=D4.x; we[13]=D4.y; we[14]=D4.z; we[15]=D4.w;
        }
        __syncthreads();

        for (int t = 0; t < TENC; ++t) {
            {   // e[j] = [h,c] @ We.T  (f16 dot2, conflict-free pr = i*8+pq)
                int bb = tid >> 9, j = r9 >> 3, pq = r9 & 7;
                float acc = 0.f;
                #pragma unroll
                for (int i = 0; i < 16; ++i)
                    acc = fdot2p(we[i], hcp[bb][i * 8 + pq], acc);
                acc += __shfl_xor(acc, 1, 8);
                acc += __shfl_xor(acc, 2, 8);
                acc += __shfl_xor(acc, 4, 8);
                if (pq == 0) ebuf[bb][j] = acc;
            }
            __syncthreads();
            if (tid < 544) {   // score[f]: 16 threads per (bb,f)
                int bb = tid / 272, r = tid - bb * 272, f = r >> 4, pp = r & 15;
                float4 wx = *(const float4*)&big[bb][f * SB + pp * 4];
                float4 e4 = *(const float4*)&ebuf[bb][pp * 4];
                float4 v4 = *(const float4*)&vw1[pp * 4];
                float acc = ftanh(wx.x + e4.x) * v4.x + ftanh(wx.y + e4.y) * v4.y
                          + ftanh(wx.z + e4.z) * v4.z + ftanh(wx.w + e4.w) * v4.w;
                acc += __shfl_xor(acc, 1, 16);
                acc += __shfl_xor(acc, 2, 16);
                acc += __shfl_xor(acc, 4, 16);
                acc += __shfl_xor(acc, 8, 16);
                if (pp == 0) sc[bb][f] = acc + Vd_b[0];
            }
            __syncthreads();
            if (tid < 128) {   // softmax(17) + pack xav pairs
                int bb = tid >> 6, l = tid & 63;
                float v = (l < NF1) ? sc[bb][l] : -1e30f;
                float m = v;
                for (int d = 32; d; d >>= 1) m = fmaxf(m, __shfl_xor(m, d, 64));
                float e = (l < NF1) ? __expf(v - m) : 0.f;
                float s = e;
                for (int d = 32; d; d >>= 1) s += __shfl_xor(s, d, 64);
                float xv = (l < NF1) ? big[bb][XIN + t * NF1 + l] * (e / s) : 0.f;
                float xp = __shfl_xor(xv, 1, 64);
                if (!(l & 1) && l < 18) xhp[bb][l >> 1] = pkh_d(xv, xp);
            }
            __syncthreads();
            {   // gates from persisted regs; x via readlane broadcast
                unsigned xA0 = xhp[0][p * 37 + lane];
                unsigned xA1 = xhp[1][p * 37 + lane];
                float a0 = bg1, a1 = bg1;
                #pragma unroll
                for (int i = 0; i < 37; ++i) {
                    unsigned s0 = __builtin_amdgcn_readlane(xA0, i);
                    unsigned s1 = __builtin_amdgcn_readlane(xA1, i);
                    a0 = fdot2p(wB[i], s0, a0);
                    a1 = fdot2p(wB[i], s1, a1);
                }
                pre2[p][0][g] = a0; pre2[p][1][g] = a1;
                // reload we for next step (latency hidden behind 2 barriers)
                const uint4* q4 = (const uint4*)(wsu + U_WE + ((r9 >> 3) << 7) + ((r9 & 7) << 4));
                uint4 A = q4[0], Bq = q4[1], C = q4[2], D4 = q4[3];
                we[0]=A.x; we[1]=A.y; we[2]=A.z; we[3]=A.w; we[4]=Bq.x; we[5]=Bq.y; we[6]=Bq.z; we[7]=Bq.w;
                we[8]=C.x; we[9]=C.y; we[10]=C.z; we[11]=C.w; we[12]=D4.x; we[13]=D4.y; we[14]=D4.z; we[15]=D4.w;
            }
            __syncthreads();
            if (tid < 256) {   // LSTM pointwise (c in register)
                int bb = tid >> 7, k = tid & 127;
                float gi = pre2[0][bb][k]       + pre2[1][bb][k];
                float gf = pre2[0][bb][128 + k] + pre2[1][bb][128 + k];
                float gg = pre2[0][bb][256 + k] + pre2[1][bb][256 + k];
                float go = pre2[0][bb][384 + k] + pre2[1][bb][384 + k];
                float c2 = fsig(gf) * creg + fsig(gi) * ftanh(gg);
                float h2v = fsig(go) * ftanh(c2);
                creg = c2;
                buf[bb][t][k] = h2v;
                float hp = __shfl_xor(h2v, 1, 64);
                float cp = __shfl_xor(c2, 1, 64);
                if (!(k & 1)) {
                    unsigned hu = pkh_d(h2v, hp);
                    hcp[bb][k >> 1] = hu;
                    hcp[bb][64 + (k >> 1)] = pkh_d(c2, cp);
                    xhp[bb][9 + (k >> 1)] = hu;
                }
            }
            __syncthreads();
        }
    }

    // ================= Phase C: Wi2X =================
    for (int i = tid; i < 16512; i += 1024) {
        int bb = i / 8256, r = i - bb * 8256, f = r >> 6, j = r & 63;
        float acc = Wi2_b[j];
        for (int tt = 0; tt < 16; ++tt) {
            float4 w = Wi2p[tt * 64 + j];
            float m0, m1, m2, m3;
            if (f < HH) {
                m0 = buf[bb][4 * tt][f];     m1 = buf[bb][4 * tt + 1][f];
                m2 = buf[bb][4 * tt + 2][f]; m3 = buf[bb][4 * tt + 3][f];
            } else {
                m0 = lab[bb][4 * tt];     m1 = lab[bb][4 * tt + 1];
                m2 = lab[bb][4 * tt + 2]; m3 = lab[bb][4 * tt + 3];
            }
            acc += m0 * w.x + m1 * w.y + m2 * w.z + m3 * w.w;
        }
        big[bb][f * SB + j] = acc;
    }

    // ================= Phase D: encoder scan 2 =================
    {
        if (tid < 130) { xhp[0][tid] = 0u; xhp[1][tid] = 0u; }
        if (tid < 128) { hcp[0][tid] = 0u; hcp[1][tid] = 0u; }
        creg = 0.f;
        unsigned wD[65];
        #pragma unroll
        for (int i = 0; i < 65; ++i) wD[i] = wsu[U_GD + i * 1024 + tid];
        unsigned we[16];
        {
            const uint4* q4 = (const uint4*)(wsu + U_WE2 + ((r9 >> 3) << 7) + ((r9 & 7) << 4));
            uint4 A = q4[0], Bq = q4[1], C = q4[2], D4 = q4[3];
            we[0]=A.x; we[1]=A.y; we[2]=A.z; we[3]=A.w; we[4]=Bq.x; we[5]=Bq.y; we[6]=Bq.z; we[7]=Bq.w;
            we[8]=C.x; we[9]=C.y; we[10]=C.z; we[11]=C.w; we[12]=D4.x; we[13]=D4.y; we[14]=D4.z; we[15]=D4.w;
        }
        __syncthreads();

        for (int t = 0; t < TENC; ++t) {
            {   // e[j] = [h,c] @ We2.T
                int bb = tid >> 9, j = r9 >> 3, pq = r9 & 7;
                float acc = 0.f;
                #pragma unroll
                for (int i = 0; i < 16; ++i)
                    acc = fdot2p(we[i], hcp[bb][i * 8 + pq], acc);
                acc += __shfl_xor(acc, 1, 8);
                acc += __shfl_xor(acc, 2, 8);
                acc += __shfl_xor(acc, 4, 8);
                if (pq == 0) ebuf[bb][j] = acc;
            }
            __syncthreads();
            for (int i = tid; i < 1032; i += 1024) {   // score[f]: 4 threads per (bb,f)
                int bb = i / 516, r = i - bb * 516, f = r >> 2, pp = i & 3;
                float acc = 0.f;
                #pragma unroll
                for (int c = 0; c < 4; ++c) {
                    float4 wx = *(const float4*)&big[bb][f * SB + pp * 16 + c * 4];
                    float4 e4 = *(const float4*)&ebuf[bb][pp * 16 + c * 4];
                    float4 v4 = *(const float4*)&vw2[pp * 16 + c * 4];
                    acc += ftanh(wx.x + e4.x) * v4.x + ftanh(wx.y + e4.y) * v4.y
                         + ftanh(wx.z + e4.z) * v4.z + ftanh(wx.w + e4.w) * v4.w;
                }
                acc += __shfl_xor(acc, 1, 4);
                acc += __shfl_xor(acc, 2, 4);
                if (pp == 0) sc[bb][f] = acc + Vd2_b[0];
            }
            __syncthreads();
            if (tid < 128) {   // softmax(129) + pack xav pairs
                int bb = tid >> 6, l = tid & 63;
                float s1 = sc[bb][l], s2 = sc[bb][l + 64];
                float s3 = (l == 0) ? sc[bb][128] : -1e30f;
                float m = fmaxf(fmaxf(s1, s2), s3);
                for (int d = 32; d; d >>= 1) m = fmaxf(m, __shfl_xor(m, d, 64));
                float e1 = __expf(s1 - m), e2 = __expf(s2 - m);
                float e3 = (l == 0) ? __expf(s3 - m) : 0.f;
                float s = e1 + e2 + e3;
                for (int d = 32; d; d >>= 1) s += __shfl_xor(s, d, 64);
                float inv = 1.f / s;
                float v1 = buf[bb][t][l] * e1 * inv;
                float v2 = buf[bb][t][l + 64] * e2 * inv;
                float v1p = __shfl_xor(v1, 1, 64);
                float v2p = __shfl_xor(v2, 1, 64);
                if (!(l & 1)) {
                    xhp[bb][l >> 1] = pkh_d(v1, v1p);
                    xhp[bb][32 + (l >> 1)] = pkh_d(v2, v2p);
                }
                if (l == 0) xhp[bb][64] = pkh_d(lab[bb][t] * e3 * inv, 0.f);
            }
            __syncthreads();
            {   // gates
                unsigned xA0 = xhp[0][p * 65 + lane];
                unsigned xA1 = xhp[1][p * 65 + lane];
                float a0 = bg2, a1 = bg2;
                #pragma unroll
                for (int i = 0; i < 64; ++i) {
                    unsigned s0 = __builtin_amdgcn_readlane(xA0, i);
                    unsigned s1 = __builtin_amdgcn_readlane(xA1, i);
                    a0 = fdot2p(wD[i], s0, a0);
                    a1 = fdot2p(wD[i], s1, a1);
                }
                {   // pair index BASE+64 (uniform broadcast read)
                    unsigned u0 = xhp[0][p * 65 + 64];
                    unsigned u1 = xhp[1][p * 65 + 64];
                    a0 = fdot2p(wD[64], u0, a0);
                    a1 = fdot2p(wD[64], u1, a1);
                }
                pre2[p][0][g] = a0; pre2[p][1][g] = a1;
                const uint4* q4 = (const uint4*)(wsu + U_WE2 + ((r9 >> 3) << 7) + ((r9 & 7) << 4));
                uint4 A = q4[0], Bq = q4[1], C = q4[2], D4 = q4[3];
                we[0]=A.x; we[1]=A.y; we[2]=A.z; we[3]=A.w; we[4]=Bq.x; we[5]=Bq.y; we[6]=Bq.z; we[7]=Bq.w;
                we[8]=C.x; we[9]=C.y; we[10]=C.z; we[11]=C.w; we[12]=D4.x; we[13]=D4.y; we[14]=D4.z; we[15]=D4.w;
            }
            __syncthreads();
            if (tid < 256) {
                int bb = tid >> 7, k = tid & 127;
                float gi = pre2[0][bb][k]       + pre2[1][bb][k];
                float gf = pre2[0][bb][128 + k] + pre2[1][bb][128 + k];
                float gg = pre2[0][bb][256 + k] + pre2[1][bb][256 + k];
                float go = pre2[0][bb][384 + k] + pre2[1][bb][384 + k];
                float c2 = fsig(gf) * creg + fsig(gi) * ftanh(gg);
                float h2v = fsig(go) * ftanh(c2);
                creg = c2;
                buf[bb][t][k] = h2v;            // final overwrites consumed mid row
                float hp = __shfl_xor(h2v, 1, 64);
                float cp = __shfl_xor(c2, 1, 64);
                if (!(k & 1)) {
                    unsigned hu = pkh_d(h2v, hp);
                    hcp[bb][k >> 1] = hu;
                    hcp[bb][64 + (k >> 1)] = pkh_d(c2, cp);
                    xhp[bb][65 + (k >> 1)] = hu;
                }
            }
            __syncthreads();
        }
    }

    // ================= Phase E: WxF =================
    for (int i = tid; i < 16384; i += 1024) {
        int bb = i >> 13, r = i & 8191, tt = r >> 7, j = r & 127;
        float acc = Wx_b[j];
        const float4* bv = (const float4*)buf[bb][tt];
        #pragma unroll 8
        for (int kk = 0; kk < 32; ++kk)
            acc += dot4(Wxp[kk * 128 + j], bv[kk]);
        big[bb][tt * SWF + j] = acc;
    }

    // ================= Phase F: decoder =================
    {
        if (tid < 130) { xhp[0][tid] = 0u; xhp[1][tid] = 0u; }
        if (tid < 128) { hcp[0][tid] = 0u; hcp[1][tid] = 0u; }
        creg = 0.f;
        unsigned wF[64];
        #pragma unroll
        for (int i = 0; i < 64; ++i) wF[i] = wsu[U_GF + i * 1024 + tid];
        unsigned wh[32];
        {
            const uint4* q4 = (const uint4*)(wsu + U_WH + ((r9 >> 2) << 7) + ((r9 & 3) << 5));
            #pragma unroll
            for (int c = 0; c < 8; ++c) {
                uint4 A = q4[c];
                wh[4*c]=A.x; wh[4*c+1]=A.y; wh[4*c+2]=A.z; wh[4*c+3]=A.w;
            }
        }
        __syncthreads();

        for (int n = 0; n < NDEC; ++n) {
            {   // e[j] = [h,c] @ Wh.T  (j<128, pq<4, pr = i*4+pq)
                int bb = tid >> 9, j = r9 >> 2, pq = r9 & 3;
                float acc = 0.f;
                #pragma unroll
                for (int i = 0; i < 32; ++i)
                    acc = fdot2p(wh[i], hcp[bb][i * 4 + pq], acc);
                acc += __shfl_xor(acc, 1, 4);
                acc += __shfl_xor(acc, 2, 4);
                if (pq == 0) ebuf[bb][j] = acc;
            }
            __syncthreads();
            {   // s[tt]: 8 threads per (bb,tt)
                int bb = tid >> 9, tt = r9 >> 3, pp = r9 & 7;
                float acc = 0.f;
                #pragma unroll
                for (int c = 0; c < 4; ++c) {
                    float4 wx = *(const float4*)&big[bb][tt * SWF + pp * 16 + c * 4];
                    float4 e4 = *(const float4*)&ebuf[bb][pp * 16 + c * 4];
                    float4 v4 = *(const float4*)&vwf[pp * 16 + c * 4];
                    acc += ftanh(wx.x + e4.x) * v4.x + ftanh(wx.y + e4.y) * v4.y
                         + ftanh(wx.z + e4.z) * v4.z + ftanh(wx.w + e4.w) * v4.w;
                }
                acc += __shfl_xor(acc, 1, 8);
                acc += __shfl_xor(acc, 2, 8);
                acc += __shfl_xor(acc, 4, 8);
                if (pp == 0) sc[bb][tt] = acc + V_b[0];
            }
            __syncthreads();
            if (tid < 128) {   // softmax(64) over time
                int bb = tid >> 6, l = tid & 63;
                float v = sc[bb][l];
                float m = v;
                for (int d = 32; d; d >>= 1) m = fmaxf(m, __shfl_xor(m, d, 64));
                float e = __expf(v - m);
                float s = e;
                for (int d = 32; d; d >>= 1) s += __shfl_xor(s, d, 64);
                att[bb][l] = e / s;
            }
            __syncthreads();
            {   // din[k] = sum_t a[t]*final[t][k]; pack pairs
                int bb = tid >> 9, k = r9 >> 2, pq = r9 & 3;
                float acc = 0.f;
                #pragma unroll
                for (int u = 0; u < 16; ++u) {
                    int tt = u * 4 + pq;
                    acc += att[bb][tt] * buf[bb][tt][k];
                }
                acc += __shfl_xor(acc, 1, 64);
                acc += __shfl_xor(acc, 2, 64);   // all 4 pq lanes now hold din_k
                float dp = __shfl_xor(acc, 4, 64);   // partner k^1
                if (pq == 0 && !(k & 1)) xhp[bb][k >> 1] = pkh_d(acc, dp);
            }
            __syncthreads();
            {   // gates
                unsigned xA0 = xhp[0][p * 64 + lane];
                unsigned xA1 = xhp[1][p * 64 + lane];
                float a0 = bgd, a1 = bgd;
                #pragma unroll
                for (int i = 0; i < 64; ++i) {
                    unsigned s0 = __builtin_amdgcn_readlane(xA0, i);
                    unsigned s1 = __builtin_amdgcn_readlane(xA1, i);
                    a0 = fdot2p(wF[i], s0, a0);
                    a1 = fdot2p(wF[i], s1, a1);
                }
                pre2[p][0][g] = a0; pre2[p][1][g] = a1;
            }
            __syncthreads();
            if (tid < 256) {   // pointwise + fused output partial
                int bb = tid >> 7, k = tid & 127;
                float gi = pre2[0][bb][k]       + pre2[1][bb][k];
                float gf = pre2[0][bb][128 + k] + pre2[1][bb][128 + k];
                float gg = pre2[0][bb][256 + k] + pre2[1][bb][256 + k];
                float go = pre2[0][bb][384 + k] + pre2[1][bb][384 + k];
                float c2 = fsig(gf) * creg + fsig(gi) * ftanh(gg);
                float h2v = fsig(go) * ftanh(c2);
                creg = c2;
                float hp = __shfl_xor(h2v, 1, 64);
                float cp = __shfl_xor(c2, 1, 64);
                if (!(k & 1)) {
                    unsigned hu = pkh_d(h2v, hp);
                    hcp[bb][k >> 1] = hu;
                    hcp[bb][64 + (k >> 1)] = pkh_d(c2, cp);
                    xhp[bb][64 + (k >> 1)] = hu;
                }
                if (n >= 6) {
                    float v = h2v * rw[k];
                    for (int d = 32; d; d >>= 1) v += __shfl_xor(v, d, 64);
                    if ((tid & 63) == 0) rsm[tid >> 6] = v;
                }
            }
            __syncthreads();
            if (n >= 6 && tid < 2)
                out[(b0 + tid) * TDEC + (n - 6)] = rsm[tid * 2] + rsm[tid * 2 + 1] + reg_b[0];
        }
    }
}

extern "C" void kernel_launch(void* const* d_in, const int* in_sizes, int n_in,
                              void* d_out, int out_size, void* d_ws, size_t ws_size,
                              hipStream_t stream)
{
    const float* inq   = (const float*)d_in[0];
    const float* labp  = (const float*)d_in[1];
    const float* Wih1  = (const float*)d_in[2];
    const float* Whh1  = (const float*)d_in[3];
    const float* bih1  = (const float*)d_in[4];
    const float* bhh1  = (const float*)d_in[5];
    const float* Wih2  = (const float*)d_in[6];
    const float* Whh2  = (const float*)d_in[7];
    const float* bih2  = (const float*)d_in[8];
    const float* bhh2  = (const float*)d_in[9];
    const float* Wihd  = (const float*)d_in[10];
    const float* Whhd  = (const float*)d_in[11];
    const float* bihd  = (const float*)d_in[12];
    const float* bhhd  = (const float*)d_in[13];
    const float* Wi_w  = (const float*)d_in[14];
    const float* Wi_b  = (const float*)d_in[15];
    const float* We_w  = (const float*)d_in[16];
    const float* Vd_w  = (const float*)d_in[17];
    const float* Vd_b  = (const float*)d_in[18];
    const float* Wi2_w = (const float*)d_in[19];
    const float* Wi2_b = (const float*)d_in[20];
    const float* We2_w = (const float*)d_in[21];
    const float* Vd2_w = (const float*)d_in[22];
    const float* Vd2_b = (const float*)d_in[23];
    const float* Wx_w  = (const float*)d_in[24];
    const float* Wx_b  = (const float*)d_in[25];
    const float* Wh_w  = (const float*)d_in[26];
    const float* V_w   = (const float*)d_in[27];
    const float* V_b   = (const float*)d_in[28];
    const float* reg_w = (const float*)d_in[29];
    const float* reg_b = (const float*)d_in[30];
    float* ws  = (float*)d_ws;
    unsigned* wsu = (unsigned*)d_ws;
    float* out = (float*)d_out;

    pack_f3<<<dim3(16, 3), 256, 0, stream>>>(Wx_w, Wi_w, Wi2_w, ws);
    pack_gate<<<37, 1024, 0, stream>>>(Wih1, Whh1, 17, 18, 73, 37, U_GB, wsu);
    pack_gate<<<65, 1024, 0, stream>>>(Wih2, Whh2, 129, 130, 129, 65, U_GD, wsu);
    pack_gate<<<64, 1024, 0, stream>>>(Wihd, Whhd, 128, 128, 128, 64, U_GF, wsu);
    pack_ew<<<8, 1024, 0, stream>>>(We_w, 64, 8, 16, U_WE, wsu);
    pack_ew<<<8, 1024, 0, stream>>>(We2_w, 64, 8, 16, U_WE2, wsu);
    pack_ew<<<16, 1024, 0, stream>>>(Wh_w, 128, 4, 32, U_WH, wsu);
    dstp_main<<<256, 1024, 0, stream>>>(inq, labp, bih1, bhh1, bih2, bhh2, bihd, bhhd,
                                        Wi_b, Vd_w, Vd_b, Wi2_b, Vd2_w, Vd2_b,
                                        Wx_b, V_w, V_b, reg_w, reg_b, ws, out);
}